// Round 16
// baseline (214.682 us; speedup 1.0000x reference)
//
#include <hip/hip_runtime.h>
#include <hip/hip_fp16.h>
#include <math.h>

// GCN 2-layer. norm_e = dinv[src]*dinv[dst] factorizes: pre-scale at source
// (gemm1 epilogue), aggregate raw, post-scale at destination.
// Proven (R10-R15, 193.7 us): fixed-region window partition via LDS FIFO ->
// block-local CSR fill -> CSR gather over 64 B uint8+scale h1 rows;
// register-resident gemm1.
// R16: agg1 VMEM-issue cut x2 -- lane = 8n+d loads dwordx2 d of neighbor n's
// row: 1 VMEM instr per 8 rows (was 4); 1 colidx dword per 8 nbrs; scale =
// .y of lane 8n+6. nt colidx loads protect h1q L2/L3 residency.

constexpr int N    = 100000;
constexpr int E    = 3200000;
constexpr int F_IN = 128;
constexpr int H    = 50;
constexpr int RB   = 64;                  // packed h1 row bytes (1 line)

constexpr int WSH  = 8;                   // window shift: 256 nodes
constexpr int WSZ  = 1 << WSH;
constexpr int NW   = (N + WSZ - 1) / WSZ; // 391 windows
constexpr int CAP  = 24;                  // FIFO capacity per window bin
constexpr int CAPW = 9216;                // fixed pair-region per window
constexpr int PART_BLK = 512;

constexpr int WS_LD = 64;

typedef int int4v __attribute__((ext_vector_type(4)));
typedef unsigned uint4v __attribute__((ext_vector_type(4)));
typedef unsigned uint2v __attribute__((ext_vector_type(2)));

// ---------------- build ----------------

__global__ __launch_bounds__(512) void k_init(int* __restrict__ gcur) {
    int i = threadIdx.x;
    if (i < NW) gcur[i] = i * CAPW;
}

// partition edges into fixed window regions; LDS FIFO -> contiguous chunks
__global__ __launch_bounds__(256) void k_part(const int* __restrict__ src,
                                              const int* __restrict__ dst,
                                              int* __restrict__ gcur,
                                              int* __restrict__ pairs) {
    __shared__ int fifo[NW][CAP];   // 37.5 KB
    __shared__ int lcnt[NW];
    const int t = threadIdx.x;
    for (int i = t; i < NW; i += 256) lcnt[i] = 0;
    __syncthreads();
    const int4v* dst4 = (const int4v*)dst;
    const int4v* src4 = (const int4v*)src;
    const long Q = E / 4;
    for (long tq = (long)blockIdx.x * 1024; tq < Q; tq += (long)gridDim.x * 1024) {
        #pragma unroll
        for (int u = 0; u < 4; ++u) {
            long q = tq + u * 256 + t;
            if (q < Q) {
                int4v d = __builtin_nontemporal_load(dst4 + q);
                int4v s = __builtin_nontemporal_load(src4 + q);
                #pragma unroll
                for (int e = 0; e < 4; ++e) {
                    int dd = (e == 0) ? d.x : (e == 1) ? d.y : (e == 2) ? d.z : d.w;
                    int ss = (e == 0) ? s.x : (e == 1) ? s.y : (e == 2) ? s.z : s.w;
                    int b  = dd >> WSH;
                    int pk = (ss << WSH) | (dd & (WSZ - 1));
                    int pos = atomicAdd(&lcnt[b], 1);
                    if (pos < CAP) fifo[b][pos] = pk;
                    else { int p = atomicAdd(&gcur[b], 1); pairs[p] = pk; }  // rare
                }
            }
        }
        __syncthreads();
        for (int b = t; b < NW; b += 256) {
            int c = lcnt[b]; if (c > CAP) c = CAP;
            if (c > 0) {
                int base = atomicAdd(&gcur[b], c);
                for (int j = 0; j < c; ++j) pairs[base + j] = fifo[b][j];
                lcnt[b] = 0;
            }
        }
        __syncthreads();
    }
}

// block per window: histogram -> scan -> rowptr/deg/dinv -> fill colidx.
__global__ __launch_bounds__(512) void k_csrfill(const int* __restrict__ pairs,
                                                 const int* __restrict__ gcur,
                                                 int* __restrict__ colidx,
                                                 int* __restrict__ rowptr,
                                                 int* __restrict__ degn,
                                                 float* __restrict__ dinv) {
    __shared__ int cnt[WSZ];
    __shared__ int cur[WSZ];
    __shared__ int wsum[4];
    const int t = threadIdx.x, w = blockIdx.x;
    if (t < WSZ) cnt[t] = 0;
    __syncthreads();
    const int p0 = w * CAPW, p1 = gcur[w];
    for (int i = p0 + t; i < p1; i += 512)
        atomicAdd(&cnt[pairs[i] & (WSZ - 1)], 1);
    __syncthreads();
    int v = 0, incl = 0;
    if (t < WSZ) {
        const int lane = t & 63, wid = t >> 6;
        v = cnt[t];
        incl = v;
        #pragma unroll
        for (int o = 1; o < 64; o <<= 1) {
            int y = __shfl_up(incl, o);
            if (lane >= o) incl += y;
        }
        if (lane == 63) wsum[wid] = incl;
    }
    __syncthreads();
    if (t < WSZ) {
        const int wid = t >> 6;
        int wbase = 0;
        #pragma unroll
        for (int u = 0; u < 4; ++u) wbase += (u < wid) ? wsum[u] : 0;
        int excl = wbase + incl - v;
        cur[t] = excl;
        int node = (w << WSH) + t;
        if (node < N) {
            rowptr[node] = p0 + excl;
            degn[node]   = v;
            dinv[node]   = rsqrtf((float)v + 1.0f);   // +1 self loop
        }
    }
    __syncthreads();
    for (int i = p0 + t; i < p1; i += 512) {
        int pk  = pairs[i];
        int pos = atomicAdd(&cur[pk & (WSZ - 1)], 1);
        colidx[p0 + pos] = pk >> WSH;
    }
}

// ---------------- compute ----------------

// h1 row (64 B): bytes 0..49 = uint8 (q+128), float scale @ byte 52.
// Register-resident: thread owns 2 rows x 16 j; W1 in LDS only.
__global__ __launch_bounds__(256) void k_gemm1(const float* __restrict__ x,
                                               const float* __restrict__ W1,
                                               const float* __restrict__ dinv,
                                               unsigned char* __restrict__ h1q) {
    __shared__ float Ws[F_IN][WS_LD];   // 32 KB, j padded to 64
    const int t = threadIdx.x;
    for (int i = t; i < F_IN * H; i += 256)
        Ws[i / H][i % H] = W1[i];
    for (int i = t; i < F_IN * (WS_LD - H); i += 256)
        Ws[i / (WS_LD - H)][H + i % (WS_LD - H)] = 0.0f;
    __syncthreads();

    const int jg = t & 3, rq = t >> 2;
    const int j0 = jg * 16;
    const long r0 = (long)blockIdx.x * 128 + rq * 2;
    if (r0 >= N) return;
    const bool v1 = (r0 + 1 < N);

    float acc0[16], acc1[16];
    #pragma unroll
    for (int u = 0; u < 16; ++u) { acc0[u] = 0.0f; acc1[u] = 0.0f; }

    const float* xr0 = x + r0 * F_IN;
    const float* xr1 = xr0 + (v1 ? F_IN : 0);

    for (int k0 = 0; k0 < F_IN; k0 += 4) {
        float4 xa = *(const float4*)(xr0 + k0);
        float4 xb = *(const float4*)(xr1 + k0);
        float ka[4] = {xa.x, xa.y, xa.z, xa.w};
        float kb[4] = {xb.x, xb.y, xb.z, xb.w};
        #pragma unroll
        for (int kk = 0; kk < 4; ++kk) {
            const float* wrow = &Ws[k0 + kk][j0];
            float4 w0 = *(const float4*)(wrow);
            float4 w1 = *(const float4*)(wrow + 4);
            float4 w2 = *(const float4*)(wrow + 8);
            float4 w3 = *(const float4*)(wrow + 12);
            float fa = ka[kk], fb = kb[kk];
            acc0[0]  += fa * w0.x; acc0[1]  += fa * w0.y;
            acc0[2]  += fa * w0.z; acc0[3]  += fa * w0.w;
            acc0[4]  += fa * w1.x; acc0[5]  += fa * w1.y;
            acc0[6]  += fa * w1.z; acc0[7]  += fa * w1.w;
            acc0[8]  += fa * w2.x; acc0[9]  += fa * w2.y;
            acc0[10] += fa * w2.z; acc0[11] += fa * w2.w;
            acc0[12] += fa * w3.x; acc0[13] += fa * w3.y;
            acc0[14] += fa * w3.z; acc0[15] += fa * w3.w;
            acc1[0]  += fb * w0.x; acc1[1]  += fb * w0.y;
            acc1[2]  += fb * w0.z; acc1[3]  += fb * w0.w;
            acc1[4]  += fb * w1.x; acc1[5]  += fb * w1.y;
            acc1[6]  += fb * w1.z; acc1[7]  += fb * w1.w;
            acc1[8]  += fb * w2.x; acc1[9]  += fb * w2.y;
            acc1[10] += fb * w2.z; acc1[11] += fb * w2.w;
            acc1[12] += fb * w3.x; acc1[13] += fb * w3.y;
            acc1[14] += fb * w3.z; acc1[15] += fb * w3.w;
        }
    }

    #pragma unroll
    for (int rr = 0; rr < 2; ++rr) {
        long gr = r0 + rr;
        if (rr == 1 && !v1) break;
        float* acc = (rr == 0) ? acc0 : acc1;
        float m = 0.0f;
        #pragma unroll
        for (int u = 0; u < 16; ++u)
            if (j0 + u < H) m = fmaxf(m, fabsf(acc[u]));
        m = fmaxf(m, __shfl_xor(m, 1));
        m = fmaxf(m, __shfl_xor(m, 2));
        m = fmaxf(m, 1e-12f);
        const float qmul  = 127.0f / m;
        const float scale = dinv[gr] * m * (1.0f / 127.0f);

        unsigned out[4] = {0u, 0u, 0u, 0u};
        #pragma unroll
        for (int u = 0; u < 16; ++u) {
            int q = 128;                   // bias: pad bytes decode to 0
            if (j0 + u < H) {
                int qi = (int)rintf(acc[u] * qmul);
                qi = max(-127, min(127, qi));
                q = qi + 128;
            }
            ((unsigned char*)out)[u] = (unsigned char)q;
        }
        if (jg == 3) out[1] = __float_as_uint(scale);   // byte 52 of row
        *(uint4v*)(h1q + gr * RB + jg * 16) = *(uint4v*)out;
    }
}

// CSR gather, 8 neighbors per wave step: lane = 8n+d loads dwordx2 d of
// neighbor n's 64 B row. Biased-ubyte decode with correction term.
__global__ __launch_bounds__(256) void k_agg1_fused(const int* __restrict__ rowptr,
                                                    const int* __restrict__ degn,
                                                    const int* __restrict__ colidx,
                                                    const unsigned char* __restrict__ h1q,
                                                    const float* __restrict__ dinv,
                                                    const float* __restrict__ b1,
                                                    const float* __restrict__ W2,
                                                    float* __restrict__ h2) {
    const int lane = threadIdx.x & 63;
    const int d = lane & 7;         // dwordx2 index in row (bytes 8d..8d+7)
    const int n = lane >> 3;        // neighbor slot 0..7
    const int scLane = (lane & 56) | 6;   // lane holding scale in .y

    // per-lane epilogue constants for features 8d..8d+7
    float b1v[8], w20[8], w21[8];
    #pragma unroll
    for (int j = 0; j < 8; ++j) {
        int f = 8 * d + j;
        bool vld = f < H;
        b1v[j] = vld ? b1[f] : 0.0f;
        w20[j] = vld ? W2[f * 2 + 0] : 0.0f;
        w21[j] = vld ? W2[f * 2 + 1] : 0.0f;
    }

    long gw = ((long)blockIdx.x * blockDim.x + threadIdx.x) >> 6;
    long nwav = ((long)gridDim.x * blockDim.x) >> 6;
    for (long i = gw; i < N; i += nwav) {
        const int start = rowptr[i];
        const int deg   = degn[i];
        float a[8];
        #pragma unroll
        for (int u = 0; u < 8; ++u) a[u] = 0.0f;
        float corr = 0.0f;

        {   // self row: only group n==0 contributes
            uint2v w = *(const uint2v*)(h1q + i * (long)RB + 8 * d);
            float sc = __uint_as_float(__shfl((int)w.y, scLane));
            if (n != 0) sc = 0.0f;
            a[0] += (float)(w.x & 0xFFu) * sc;
            a[1] += (float)((w.x >> 8) & 0xFFu) * sc;
            a[2] += (float)((w.x >> 16) & 0xFFu) * sc;
            a[3] += (float)(w.x >> 24) * sc;
            a[4] += (float)(w.y & 0xFFu) * sc;
            a[5] += (float)((w.y >> 8) & 0xFFu) * sc;
            a[6] += (float)((w.y >> 16) & 0xFFu) * sc;
            a[7] += (float)(w.y >> 24) * sc;
            corr += sc;
        }
        int k = 0;
        for (; k + 16 <= deg; k += 16) {        // 2 independent 8-row loads
            int ia = __builtin_nontemporal_load(colidx + start + k + n);
            int ib = __builtin_nontemporal_load(colidx + start + k + 8 + n);
            uint2v wa = *(const uint2v*)(h1q + (long)ia * RB + 8 * d);
            uint2v wb = *(const uint2v*)(h1q + (long)ib * RB + 8 * d);
            float sa = __uint_as_float(__shfl((int)wa.y, scLane));
            float sb = __uint_as_float(__shfl((int)wb.y, scLane));
            a[0] += (float)(wa.x & 0xFFu) * sa;
            a[1] += (float)((wa.x >> 8) & 0xFFu) * sa;
            a[2] += (float)((wa.x >> 16) & 0xFFu) * sa;
            a[3] += (float)(wa.x >> 24) * sa;
            a[4] += (float)(wa.y & 0xFFu) * sa;
            a[5] += (float)((wa.y >> 8) & 0xFFu) * sa;
            a[6] += (float)((wa.y >> 16) & 0xFFu) * sa;
            a[7] += (float)(wa.y >> 24) * sa;
            corr += sa;
            a[0] += (float)(wb.x & 0xFFu) * sb;
            a[1] += (float)((wb.x >> 8) & 0xFFu) * sb;
            a[2] += (float)((wb.x >> 16) & 0xFFu) * sb;
            a[3] += (float)(wb.x >> 24) * sb;
            a[4] += (float)(wb.y & 0xFFu) * sb;
            a[5] += (float)((wb.y >> 8) & 0xFFu) * sb;
            a[6] += (float)((wb.y >> 16) & 0xFFu) * sb;
            a[7] += (float)(wb.y >> 24) * sb;
            corr += sb;
        }
        for (; k < deg; k += 8) {
            int kk = k + n;
            int idx = __builtin_nontemporal_load(colidx + start + min(kk, deg - 1));
            uint2v w = *(const uint2v*)(h1q + (long)idx * RB + 8 * d);
            float sc = __uint_as_float(__shfl((int)w.y, scLane));
            if (kk >= deg) sc = 0.0f;
            a[0] += (float)(w.x & 0xFFu) * sc;
            a[1] += (float)((w.x >> 8) & 0xFFu) * sc;
            a[2] += (float)((w.x >> 16) & 0xFFu) * sc;
            a[3] += (float)(w.x >> 24) * sc;
            a[4] += (float)(w.y & 0xFFu) * sc;
            a[5] += (float)((w.y >> 8) & 0xFFu) * sc;
            a[6] += (float)((w.y >> 16) & 0xFFu) * sc;
            a[7] += (float)(w.y >> 24) * sc;
            corr += sc;
        }
        #pragma unroll
        for (int u = 0; u < 8; ++u) a[u] -= 128.0f * corr;
        // reduce across the 8 neighbor groups
        #pragma unroll
        for (int o = 8; o <= 32; o <<= 1) {
            #pragma unroll
            for (int u = 0; u < 8; ++u) a[u] += __shfl_xor(a[u], o);
        }
        float di = dinv[i];
        float p0 = 0.0f, p1 = 0.0f;
        #pragma unroll
        for (int u = 0; u < 8; ++u) {
            float z = fmaxf(di * a[u] + b1v[u], 0.0f);
            p0 += z * w20[u];
            p1 += z * w21[u];
        }
        #pragma unroll
        for (int o = 1; o <= 4; o <<= 1) {
            p0 += __shfl_xor(p0, o);
            p1 += __shfl_xor(p1, o);
        }
        if (lane == 0) {
            h2[i * 2 + 0] = di * p0;
            h2[i * 2 + 1] = di * p1;
        }
    }
}

// CSR wave-per-node, lanes over edges: out = log_softmax(di*(sum+self)+b2)
__global__ __launch_bounds__(256) void k_agg2_final(const int* __restrict__ rowptr,
                                                    const int* __restrict__ degn,
                                                    const int* __restrict__ colidx,
                                                    const float* __restrict__ h2,
                                                    const float* __restrict__ dinv,
                                                    const float* __restrict__ b2,
                                                    float* __restrict__ out) {
    const int lane = threadIdx.x & 63;
    long gw = ((long)blockIdx.x * blockDim.x + threadIdx.x) >> 6;
    long nwav = ((long)gridDim.x * blockDim.x) >> 6;
    for (long i = gw; i < N; i += nwav) {
        const int start = rowptr[i];
        const int deg   = degn[i];
        float s0 = 0.0f, s1 = 0.0f;
        for (int k = lane; k < deg; k += 64) {
            int s = __builtin_nontemporal_load(colidx + start + k);
            s0 += h2[(long)s * 2 + 0];
            s1 += h2[(long)s * 2 + 1];
        }
        #pragma unroll
        for (int o = 32; o > 0; o >>= 1) {
            s0 += __shfl_xor(s0, o);
            s1 += __shfl_xor(s1, o);
        }
        if (lane == 0) {
            float di = dinv[i];
            float a0 = di * (s0 + h2[i * 2 + 0]) + b2[0];
            float a1 = di * (s1 + h2[i * 2 + 1]) + b2[1];
            float m = fmaxf(a0, a1);
            float lse = m + logf(expf(a0 - m) + expf(a1 - m));
            out[i * 2 + 0] = a0 - lse;
            out[i * 2 + 1] = a1 - lse;
        }
    }
}

extern "C" void kernel_launch(void* const* d_in, const int* in_sizes, int n_in,
                              void* d_out, int out_size, void* d_ws, size_t ws_size,
                              hipStream_t stream) {
    const float* x  = (const float*)d_in[0];
    const int*   ei = (const int*)d_in[1];   // [2][E]: row0 src, row1 dst
    const float* W1 = (const float*)d_in[2];
    const float* b1 = (const float*)d_in[3];
    const float* W2 = (const float*)d_in[4];
    const float* b2 = (const float*)d_in[5];
    float* out = (float*)d_out;

    const int* src = ei;
    const int* dst = ei + E;

    // ws layout
    int*    gcur   = (int*)d_ws;                       // 400
    int*    rowptr = gcur + 400;                       // N
    int*    degn   = rowptr + N;                       // N
    float*  dinv   = (float*)(degn + N);               // N
    int*    pairs  = (int*)(dinv + N);                 // NW*CAPW (14.4 MB)
    int*    colidx = pairs + (long)NW * CAPW;          // NW*CAPW (14.4 MB)
    unsigned char* h1q = (unsigned char*)(colidx + (long)NW * CAPW);  // 6.4 MB
    float*  h2     = (float*)(h1q + (long)N * RB);     // N*2  (~37 MB total)

    k_init<<<1, 512, 0, stream>>>(gcur);
    k_part<<<PART_BLK, 256, 0, stream>>>(src, dst, gcur, pairs);
    k_csrfill<<<NW, 512, 0, stream>>>(pairs, gcur, colidx, rowptr, degn, dinv);
    k_gemm1<<<(N + 127) / 128, 256, 0, stream>>>(x, W1, dinv, h1q);
    k_agg1_fused<<<4096, 256, 0, stream>>>(rowptr, degn, colidx, h1q, dinv, b1, W2, h2);
    k_agg2_final<<<2048, 256, 0, stream>>>(rowptr, degn, colidx, h2, dinv, b2, out);
}

// Round 17
// 206.827 us; speedup vs baseline: 1.0380x; 1.0380x over previous
//
#include <hip/hip_runtime.h>
#include <hip/hip_fp16.h>
#include <math.h>

// GCN 2-layer. norm_e = dinv[src]*dinv[dst] factorizes: pre-scale at source
// (gemm1 epilogue), aggregate raw, post-scale at destination.
// Proven (R10-R15, 193.7 us): fixed-region window partition via LDS FIFO ->
// block-local CSR fill -> CSR gather with 4-neighbor coalesced dword loads
// over 64 B uint8+scale h1 rows; register-resident gemm1.
// R16 (dwordx2 8-neighbor) regressed (occ 52%, heavy shfl epilogue) -> R17
// reverts agg1/agg2 to R15 form; deltas: nt colidx loads (protect h1q L2/L3
// residency) + int4 pairs read in csrfill histogram pass.

constexpr int N    = 100000;
constexpr int E    = 3200000;
constexpr int F_IN = 128;
constexpr int H    = 50;
constexpr int RB   = 64;                  // packed h1 row bytes (1 line)

constexpr int WSH  = 8;                   // window shift: 256 nodes
constexpr int WSZ  = 1 << WSH;
constexpr int NW   = (N + WSZ - 1) / WSZ; // 391 windows
constexpr int CAP  = 24;                  // FIFO capacity per window bin
constexpr int CAPW = 9216;                // fixed pair-region per window
constexpr int PART_BLK = 512;

constexpr int WS_LD = 64;

typedef int int4v __attribute__((ext_vector_type(4)));
typedef unsigned uint4v __attribute__((ext_vector_type(4)));

// ---------------- build ----------------

__global__ __launch_bounds__(512) void k_init(int* __restrict__ gcur) {
    int i = threadIdx.x;
    if (i < NW) gcur[i] = i * CAPW;
}

// partition edges into fixed window regions; LDS FIFO -> contiguous chunks
__global__ __launch_bounds__(256) void k_part(const int* __restrict__ src,
                                              const int* __restrict__ dst,
                                              int* __restrict__ gcur,
                                              int* __restrict__ pairs) {
    __shared__ int fifo[NW][CAP];   // 37.5 KB
    __shared__ int lcnt[NW];
    const int t = threadIdx.x;
    for (int i = t; i < NW; i += 256) lcnt[i] = 0;
    __syncthreads();
    const int4v* dst4 = (const int4v*)dst;
    const int4v* src4 = (const int4v*)src;
    const long Q = E / 4;
    for (long tq = (long)blockIdx.x * 1024; tq < Q; tq += (long)gridDim.x * 1024) {
        #pragma unroll
        for (int u = 0; u < 4; ++u) {
            long q = tq + u * 256 + t;
            if (q < Q) {
                int4v d = __builtin_nontemporal_load(dst4 + q);
                int4v s = __builtin_nontemporal_load(src4 + q);
                #pragma unroll
                for (int e = 0; e < 4; ++e) {
                    int dd = (e == 0) ? d.x : (e == 1) ? d.y : (e == 2) ? d.z : d.w;
                    int ss = (e == 0) ? s.x : (e == 1) ? s.y : (e == 2) ? s.z : s.w;
                    int b  = dd >> WSH;
                    int pk = (ss << WSH) | (dd & (WSZ - 1));
                    int pos = atomicAdd(&lcnt[b], 1);
                    if (pos < CAP) fifo[b][pos] = pk;
                    else { int p = atomicAdd(&gcur[b], 1); pairs[p] = pk; }  // rare
                }
            }
        }
        __syncthreads();
        for (int b = t; b < NW; b += 256) {
            int c = lcnt[b]; if (c > CAP) c = CAP;
            if (c > 0) {
                int base = atomicAdd(&gcur[b], c);
                for (int j = 0; j < c; ++j) pairs[base + j] = fifo[b][j];
                lcnt[b] = 0;
            }
        }
        __syncthreads();
    }
}

// block per window: histogram -> scan -> rowptr/deg/dinv -> fill colidx.
__global__ __launch_bounds__(512) void k_csrfill(const int* __restrict__ pairs,
                                                 const int* __restrict__ gcur,
                                                 int* __restrict__ colidx,
                                                 int* __restrict__ rowptr,
                                                 int* __restrict__ degn,
                                                 float* __restrict__ dinv) {
    __shared__ int cnt[WSZ];
    __shared__ int cur[WSZ];
    __shared__ int wsum[4];
    const int t = threadIdx.x, w = blockIdx.x;
    if (t < WSZ) cnt[t] = 0;
    __syncthreads();
    const int p0 = w * CAPW, p1 = gcur[w];
    // histogram pass: int4 reads (p0 is 16B-aligned: CAPW % 4 == 0)
    {
        const int nq = (p1 - p0) / 4;
        const int4v* pq = (const int4v*)(pairs + p0);
        for (int i = t; i < nq; i += 512) {
            int4v pk4 = pq[i];
            atomicAdd(&cnt[pk4.x & (WSZ - 1)], 1);
            atomicAdd(&cnt[pk4.y & (WSZ - 1)], 1);
            atomicAdd(&cnt[pk4.z & (WSZ - 1)], 1);
            atomicAdd(&cnt[pk4.w & (WSZ - 1)], 1);
        }
        for (int i = p0 + nq * 4 + t; i < p1; i += 512)
            atomicAdd(&cnt[pairs[i] & (WSZ - 1)], 1);
    }
    __syncthreads();
    int v = 0, incl = 0;
    if (t < WSZ) {
        const int lane = t & 63, wid = t >> 6;
        v = cnt[t];
        incl = v;
        #pragma unroll
        for (int o = 1; o < 64; o <<= 1) {
            int y = __shfl_up(incl, o);
            if (lane >= o) incl += y;
        }
        if (lane == 63) wsum[wid] = incl;
    }
    __syncthreads();
    if (t < WSZ) {
        const int wid = t >> 6;
        int wbase = 0;
        #pragma unroll
        for (int u = 0; u < 4; ++u) wbase += (u < wid) ? wsum[u] : 0;
        int excl = wbase + incl - v;
        cur[t] = excl;
        int node = (w << WSH) + t;
        if (node < N) {
            rowptr[node] = p0 + excl;
            degn[node]   = v;
            dinv[node]   = rsqrtf((float)v + 1.0f);   // +1 self loop
        }
    }
    __syncthreads();
    for (int i = p0 + t; i < p1; i += 512) {
        int pk  = pairs[i];
        int pos = atomicAdd(&cur[pk & (WSZ - 1)], 1);
        colidx[p0 + pos] = pk >> WSH;
    }
}

// ---------------- compute ----------------

// h1 row (64 B): bytes 0..49 = uint8 (q+128), float scale @ byte 52.
// Register-resident: thread owns 2 rows x 16 j; W1 in LDS only.
__global__ __launch_bounds__(256) void k_gemm1(const float* __restrict__ x,
                                               const float* __restrict__ W1,
                                               const float* __restrict__ dinv,
                                               unsigned char* __restrict__ h1q) {
    __shared__ float Ws[F_IN][WS_LD];   // 32 KB, j padded to 64
    const int t = threadIdx.x;
    for (int i = t; i < F_IN * H; i += 256)
        Ws[i / H][i % H] = W1[i];
    for (int i = t; i < F_IN * (WS_LD - H); i += 256)
        Ws[i / (WS_LD - H)][H + i % (WS_LD - H)] = 0.0f;
    __syncthreads();

    const int jg = t & 3, rq = t >> 2;
    const int j0 = jg * 16;
    const long r0 = (long)blockIdx.x * 128 + rq * 2;
    if (r0 >= N) return;
    const bool v1 = (r0 + 1 < N);

    float acc0[16], acc1[16];
    #pragma unroll
    for (int u = 0; u < 16; ++u) { acc0[u] = 0.0f; acc1[u] = 0.0f; }

    const float* xr0 = x + r0 * F_IN;
    const float* xr1 = xr0 + (v1 ? F_IN : 0);

    for (int k0 = 0; k0 < F_IN; k0 += 4) {
        float4 xa = *(const float4*)(xr0 + k0);
        float4 xb = *(const float4*)(xr1 + k0);
        float ka[4] = {xa.x, xa.y, xa.z, xa.w};
        float kb[4] = {xb.x, xb.y, xb.z, xb.w};
        #pragma unroll
        for (int kk = 0; kk < 4; ++kk) {
            const float* wrow = &Ws[k0 + kk][j0];
            float4 w0 = *(const float4*)(wrow);
            float4 w1 = *(const float4*)(wrow + 4);
            float4 w2 = *(const float4*)(wrow + 8);
            float4 w3 = *(const float4*)(wrow + 12);
            float fa = ka[kk], fb = kb[kk];
            acc0[0]  += fa * w0.x; acc0[1]  += fa * w0.y;
            acc0[2]  += fa * w0.z; acc0[3]  += fa * w0.w;
            acc0[4]  += fa * w1.x; acc0[5]  += fa * w1.y;
            acc0[6]  += fa * w1.z; acc0[7]  += fa * w1.w;
            acc0[8]  += fa * w2.x; acc0[9]  += fa * w2.y;
            acc0[10] += fa * w2.z; acc0[11] += fa * w2.w;
            acc0[12] += fa * w3.x; acc0[13] += fa * w3.y;
            acc0[14] += fa * w3.z; acc0[15] += fa * w3.w;
            acc1[0]  += fb * w0.x; acc1[1]  += fb * w0.y;
            acc1[2]  += fb * w0.z; acc1[3]  += fb * w0.w;
            acc1[4]  += fb * w1.x; acc1[5]  += fb * w1.y;
            acc1[6]  += fb * w1.z; acc1[7]  += fb * w1.w;
            acc1[8]  += fb * w2.x; acc1[9]  += fb * w2.y;
            acc1[10] += fb * w2.z; acc1[11] += fb * w2.w;
            acc1[12] += fb * w3.x; acc1[13] += fb * w3.y;
            acc1[14] += fb * w3.z; acc1[15] += fb * w3.w;
        }
    }

    #pragma unroll
    for (int rr = 0; rr < 2; ++rr) {
        long gr = r0 + rr;
        if (rr == 1 && !v1) break;
        float* acc = (rr == 0) ? acc0 : acc1;
        float m = 0.0f;
        #pragma unroll
        for (int u = 0; u < 16; ++u)
            if (j0 + u < H) m = fmaxf(m, fabsf(acc[u]));
        m = fmaxf(m, __shfl_xor(m, 1));
        m = fmaxf(m, __shfl_xor(m, 2));
        m = fmaxf(m, 1e-12f);
        const float qmul  = 127.0f / m;
        const float scale = dinv[gr] * m * (1.0f / 127.0f);

        unsigned out[4] = {0u, 0u, 0u, 0u};
        #pragma unroll
        for (int u = 0; u < 16; ++u) {
            int q = 128;                   // bias: pad bytes decode to 0
            if (j0 + u < H) {
                int qi = (int)rintf(acc[u] * qmul);
                qi = max(-127, min(127, qi));
                q = qi + 128;
            }
            ((unsigned char*)out)[u] = (unsigned char)q;
        }
        if (jg == 3) out[1] = __float_as_uint(scale);   // byte 52 of row
        *(uint4v*)(h1q + gr * RB + jg * 16) = *(uint4v*)out;
    }
}

// CSR gather, 4 neighbors per wave step (R15-proven): lane = 16n+d loads
// dword d of neighbor n's 64 B row. Biased-ubyte decode + correction term.
__global__ __launch_bounds__(256) void k_agg1_fused(const int* __restrict__ rowptr,
                                                    const int* __restrict__ degn,
                                                    const int* __restrict__ colidx,
                                                    const unsigned char* __restrict__ h1q,
                                                    const float* __restrict__ dinv,
                                                    const float* __restrict__ b1,
                                                    const float* __restrict__ W2,
                                                    float* __restrict__ h2) {
    const int lane = threadIdx.x & 63;
    const int d = lane & 15;        // dword index in row
    const int n = lane >> 4;        // neighbor slot 0..3
    const int scLane = (lane & 48) | 13;

    float b1v[4], w20[4], w21[4];
    #pragma unroll
    for (int j = 0; j < 4; ++j) {
        int f = 4 * d + j;
        bool vld = f < H;
        b1v[j] = vld ? b1[f] : 0.0f;
        w20[j] = vld ? W2[f * 2 + 0] : 0.0f;
        w21[j] = vld ? W2[f * 2 + 1] : 0.0f;
    }

    long gw = ((long)blockIdx.x * blockDim.x + threadIdx.x) >> 6;
    long nwav = ((long)gridDim.x * blockDim.x) >> 6;
    for (long i = gw; i < N; i += nwav) {
        const int start = rowptr[i];
        const int deg   = degn[i];
        float a0 = 0.f, a1 = 0.f, a2 = 0.f, a3 = 0.f, corr = 0.f;

        {   // self row: only group n==0 contributes
            unsigned w = *(const unsigned*)(h1q + i * (long)RB + 4 * d);
            float sc = __uint_as_float(__shfl((int)w, scLane));
            if (n != 0) sc = 0.0f;
            a0 += (float)(w & 0xFFu) * sc;
            a1 += (float)((w >> 8) & 0xFFu) * sc;
            a2 += (float)((w >> 16) & 0xFFu) * sc;
            a3 += (float)(w >> 24) * sc;
            corr += sc;
        }
        int k = 0;
        for (; k + 8 <= deg; k += 8) {              // 2 independent 4-row loads
            int ia = __builtin_nontemporal_load(colidx + start + k + n);
            int ib = __builtin_nontemporal_load(colidx + start + k + 4 + n);
            unsigned wa = *(const unsigned*)(h1q + (long)ia * RB + 4 * d);
            unsigned wb = *(const unsigned*)(h1q + (long)ib * RB + 4 * d);
            float sa = __uint_as_float(__shfl((int)wa, scLane));
            float sb = __uint_as_float(__shfl((int)wb, scLane));
            a0 += (float)(wa & 0xFFu) * sa;
            a1 += (float)((wa >> 8) & 0xFFu) * sa;
            a2 += (float)((wa >> 16) & 0xFFu) * sa;
            a3 += (float)(wa >> 24) * sa;
            corr += sa;
            a0 += (float)(wb & 0xFFu) * sb;
            a1 += (float)((wb >> 8) & 0xFFu) * sb;
            a2 += (float)((wb >> 16) & 0xFFu) * sb;
            a3 += (float)(wb >> 24) * sb;
            corr += sb;
        }
        for (; k < deg; k += 4) {
            int kk = k + n;
            int idx = __builtin_nontemporal_load(colidx + start + min(kk, deg - 1));
            unsigned w = *(const unsigned*)(h1q + (long)idx * RB + 4 * d);
            float sc = __uint_as_float(__shfl((int)w, scLane));
            if (kk >= deg) sc = 0.0f;
            a0 += (float)(w & 0xFFu) * sc;
            a1 += (float)((w >> 8) & 0xFFu) * sc;
            a2 += (float)((w >> 16) & 0xFFu) * sc;
            a3 += (float)(w >> 24) * sc;
            corr += sc;
        }
        a0 -= 128.0f * corr;
        a1 -= 128.0f * corr;
        a2 -= 128.0f * corr;
        a3 -= 128.0f * corr;
        #pragma unroll
        for (int o = 16; o <= 32; o <<= 1) {
            a0 += __shfl_xor(a0, o);
            a1 += __shfl_xor(a1, o);
            a2 += __shfl_xor(a2, o);
            a3 += __shfl_xor(a3, o);
        }
        float di = dinv[i];
        float z0 = fmaxf(di * a0 + b1v[0], 0.0f);
        float z1 = fmaxf(di * a1 + b1v[1], 0.0f);
        float z2 = fmaxf(di * a2 + b1v[2], 0.0f);
        float z3 = fmaxf(di * a3 + b1v[3], 0.0f);
        float p0 = z0 * w20[0] + z1 * w20[1] + z2 * w20[2] + z3 * w20[3];
        float p1 = z0 * w21[0] + z1 * w21[1] + z2 * w21[2] + z3 * w21[3];
        #pragma unroll
        for (int o = 1; o <= 8; o <<= 1) {
            p0 += __shfl_xor(p0, o);
            p1 += __shfl_xor(p1, o);
        }
        if (lane == 0) {
            h2[i * 2 + 0] = di * p0;
            h2[i * 2 + 1] = di * p1;
        }
    }
}

// CSR wave-per-node, lanes over edges: out = log_softmax(di*(sum+self)+b2)
__global__ __launch_bounds__(256) void k_agg2_final(const int* __restrict__ rowptr,
                                                    const int* __restrict__ degn,
                                                    const int* __restrict__ colidx,
                                                    const float* __restrict__ h2,
                                                    const float* __restrict__ dinv,
                                                    const float* __restrict__ b2,
                                                    float* __restrict__ out) {
    const int lane = threadIdx.x & 63;
    long gw = ((long)blockIdx.x * blockDim.x + threadIdx.x) >> 6;
    long nwav = ((long)gridDim.x * blockDim.x) >> 6;
    for (long i = gw; i < N; i += nwav) {
        const int start = rowptr[i];
        const int deg   = degn[i];
        float s0 = 0.0f, s1 = 0.0f;
        for (int k = lane; k < deg; k += 64) {
            int s = __builtin_nontemporal_load(colidx + start + k);
            s0 += h2[(long)s * 2 + 0];
            s1 += h2[(long)s * 2 + 1];
        }
        #pragma unroll
        for (int o = 32; o > 0; o >>= 1) {
            s0 += __shfl_xor(s0, o);
            s1 += __shfl_xor(s1, o);
        }
        if (lane == 0) {
            float di = dinv[i];
            float a0 = di * (s0 + h2[i * 2 + 0]) + b2[0];
            float a1 = di * (s1 + h2[i * 2 + 1]) + b2[1];
            float m = fmaxf(a0, a1);
            float lse = m + logf(expf(a0 - m) + expf(a1 - m));
            out[i * 2 + 0] = a0 - lse;
            out[i * 2 + 1] = a1 - lse;
        }
    }
}

extern "C" void kernel_launch(void* const* d_in, const int* in_sizes, int n_in,
                              void* d_out, int out_size, void* d_ws, size_t ws_size,
                              hipStream_t stream) {
    const float* x  = (const float*)d_in[0];
    const int*   ei = (const int*)d_in[1];   // [2][E]: row0 src, row1 dst
    const float* W1 = (const float*)d_in[2];
    const float* b1 = (const float*)d_in[3];
    const float* W2 = (const float*)d_in[4];
    const float* b2 = (const float*)d_in[5];
    float* out = (float*)d_out;

    const int* src = ei;
    const int* dst = ei + E;

    // ws layout
    int*    gcur   = (int*)d_ws;                       // 400
    int*    rowptr = gcur + 400;                       // N
    int*    degn   = rowptr + N;                       // N
    float*  dinv   = (float*)(degn + N);               // N
    int*    pairs  = (int*)(dinv + N);                 // NW*CAPW (14.4 MB)
    int*    colidx = pairs + (long)NW * CAPW;          // NW*CAPW (14.4 MB)
    unsigned char* h1q = (unsigned char*)(colidx + (long)NW * CAPW);  // 6.4 MB
    float*  h2     = (float*)(h1q + (long)N * RB);     // N*2  (~37 MB total)

    k_init<<<1, 512, 0, stream>>>(gcur);
    k_part<<<PART_BLK, 256, 0, stream>>>(src, dst, gcur, pairs);
    k_csrfill<<<NW, 512, 0, stream>>>(pairs, gcur, colidx, rowptr, degn, dinv);
    k_gemm1<<<(N + 127) / 128, 256, 0, stream>>>(x, W1, dinv, h1q);
    k_agg1_fused<<<4096, 256, 0, stream>>>(rowptr, degn, colidx, h1q, dinv, b1, W2, h2);
    k_agg2_final<<<2048, 256, 0, stream>>>(rowptr, degn, colidx, h2, dinv, b2, out);
}

// Round 18
// 190.909 us; speedup vs baseline: 1.1245x; 1.0834x over previous
//
#include <hip/hip_runtime.h>
#include <hip/hip_fp16.h>
#include <math.h>

// GCN 2-layer. norm_e = dinv[src]*dinv[dst] factorizes: pre-scale at source
// (gemm1 epilogue), aggregate raw, post-scale at destination.
// Proven (R10-R15, 193.7 us): fixed-region window partition via LDS FIFO ->
// block-local CSR fill -> CSR gather with 4-neighbor coalesced dword loads
// over 64 B uint8+scale h1 rows; register-resident gemm1.
// R16 (8-nbr dwordx2: occ 52%) and R17 (nt colidx: line-reuse broken,
// FETCH +9 MB) both regressed -> R18 = exact R15 agg1/agg2 (plain colidx
// loads, 24 VGPR / 73% occ sweet spot) + csrfill int4 histogram pass only.

constexpr int N    = 100000;
constexpr int E    = 3200000;
constexpr int F_IN = 128;
constexpr int H    = 50;
constexpr int RB   = 64;                  // packed h1 row bytes (1 line)

constexpr int WSH  = 8;                   // window shift: 256 nodes
constexpr int WSZ  = 1 << WSH;
constexpr int NW   = (N + WSZ - 1) / WSZ; // 391 windows
constexpr int CAP  = 24;                  // FIFO capacity per window bin
constexpr int CAPW = 9216;                // fixed pair-region per window
constexpr int PART_BLK = 512;

constexpr int WS_LD = 64;

typedef int int4v __attribute__((ext_vector_type(4)));
typedef unsigned uint4v __attribute__((ext_vector_type(4)));

// ---------------- build ----------------

__global__ __launch_bounds__(512) void k_init(int* __restrict__ gcur) {
    int i = threadIdx.x;
    if (i < NW) gcur[i] = i * CAPW;
}

// partition edges into fixed window regions; LDS FIFO -> contiguous chunks
__global__ __launch_bounds__(256) void k_part(const int* __restrict__ src,
                                              const int* __restrict__ dst,
                                              int* __restrict__ gcur,
                                              int* __restrict__ pairs) {
    __shared__ int fifo[NW][CAP];   // 37.5 KB
    __shared__ int lcnt[NW];
    const int t = threadIdx.x;
    for (int i = t; i < NW; i += 256) lcnt[i] = 0;
    __syncthreads();
    const int4v* dst4 = (const int4v*)dst;
    const int4v* src4 = (const int4v*)src;
    const long Q = E / 4;
    for (long tq = (long)blockIdx.x * 1024; tq < Q; tq += (long)gridDim.x * 1024) {
        #pragma unroll
        for (int u = 0; u < 4; ++u) {
            long q = tq + u * 256 + t;
            if (q < Q) {
                int4v d = __builtin_nontemporal_load(dst4 + q);
                int4v s = __builtin_nontemporal_load(src4 + q);
                #pragma unroll
                for (int e = 0; e < 4; ++e) {
                    int dd = (e == 0) ? d.x : (e == 1) ? d.y : (e == 2) ? d.z : d.w;
                    int ss = (e == 0) ? s.x : (e == 1) ? s.y : (e == 2) ? s.z : s.w;
                    int b  = dd >> WSH;
                    int pk = (ss << WSH) | (dd & (WSZ - 1));
                    int pos = atomicAdd(&lcnt[b], 1);
                    if (pos < CAP) fifo[b][pos] = pk;
                    else { int p = atomicAdd(&gcur[b], 1); pairs[p] = pk; }  // rare
                }
            }
        }
        __syncthreads();
        for (int b = t; b < NW; b += 256) {
            int c = lcnt[b]; if (c > CAP) c = CAP;
            if (c > 0) {
                int base = atomicAdd(&gcur[b], c);
                for (int j = 0; j < c; ++j) pairs[base + j] = fifo[b][j];
                lcnt[b] = 0;
            }
        }
        __syncthreads();
    }
}

// block per window: histogram -> scan -> rowptr/deg/dinv -> fill colidx.
__global__ __launch_bounds__(512) void k_csrfill(const int* __restrict__ pairs,
                                                 const int* __restrict__ gcur,
                                                 int* __restrict__ colidx,
                                                 int* __restrict__ rowptr,
                                                 int* __restrict__ degn,
                                                 float* __restrict__ dinv) {
    __shared__ int cnt[WSZ];
    __shared__ int cur[WSZ];
    __shared__ int wsum[4];
    const int t = threadIdx.x, w = blockIdx.x;
    if (t < WSZ) cnt[t] = 0;
    __syncthreads();
    const int p0 = w * CAPW, p1 = gcur[w];
    // histogram pass: int4 reads (p0 is 16B-aligned: CAPW % 4 == 0)
    {
        const int nq = (p1 - p0) / 4;
        const int4v* pq = (const int4v*)(pairs + p0);
        for (int i = t; i < nq; i += 512) {
            int4v pk4 = pq[i];
            atomicAdd(&cnt[pk4.x & (WSZ - 1)], 1);
            atomicAdd(&cnt[pk4.y & (WSZ - 1)], 1);
            atomicAdd(&cnt[pk4.z & (WSZ - 1)], 1);
            atomicAdd(&cnt[pk4.w & (WSZ - 1)], 1);
        }
        for (int i = p0 + nq * 4 + t; i < p1; i += 512)
            atomicAdd(&cnt[pairs[i] & (WSZ - 1)], 1);
    }
    __syncthreads();
    int v = 0, incl = 0;
    if (t < WSZ) {
        const int lane = t & 63, wid = t >> 6;
        v = cnt[t];
        incl = v;
        #pragma unroll
        for (int o = 1; o < 64; o <<= 1) {
            int y = __shfl_up(incl, o);
            if (lane >= o) incl += y;
        }
        if (lane == 63) wsum[wid] = incl;
    }
    __syncthreads();
    if (t < WSZ) {
        const int wid = t >> 6;
        int wbase = 0;
        #pragma unroll
        for (int u = 0; u < 4; ++u) wbase += (u < wid) ? wsum[u] : 0;
        int excl = wbase + incl - v;
        cur[t] = excl;
        int node = (w << WSH) + t;
        if (node < N) {
            rowptr[node] = p0 + excl;
            degn[node]   = v;
            dinv[node]   = rsqrtf((float)v + 1.0f);   // +1 self loop
        }
    }
    __syncthreads();
    for (int i = p0 + t; i < p1; i += 512) {
        int pk  = pairs[i];
        int pos = atomicAdd(&cur[pk & (WSZ - 1)], 1);
        colidx[p0 + pos] = pk >> WSH;
    }
}

// ---------------- compute ----------------

// h1 row (64 B): bytes 0..49 = uint8 (q+128), float scale @ byte 52.
// Register-resident: thread owns 2 rows x 16 j; W1 in LDS only.
__global__ __launch_bounds__(256) void k_gemm1(const float* __restrict__ x,
                                               const float* __restrict__ W1,
                                               const float* __restrict__ dinv,
                                               unsigned char* __restrict__ h1q) {
    __shared__ float Ws[F_IN][WS_LD];   // 32 KB, j padded to 64
    const int t = threadIdx.x;
    for (int i = t; i < F_IN * H; i += 256)
        Ws[i / H][i % H] = W1[i];
    for (int i = t; i < F_IN * (WS_LD - H); i += 256)
        Ws[i / (WS_LD - H)][H + i % (WS_LD - H)] = 0.0f;
    __syncthreads();

    const int jg = t & 3, rq = t >> 2;
    const int j0 = jg * 16;
    const long r0 = (long)blockIdx.x * 128 + rq * 2;
    if (r0 >= N) return;
    const bool v1 = (r0 + 1 < N);

    float acc0[16], acc1[16];
    #pragma unroll
    for (int u = 0; u < 16; ++u) { acc0[u] = 0.0f; acc1[u] = 0.0f; }

    const float* xr0 = x + r0 * F_IN;
    const float* xr1 = xr0 + (v1 ? F_IN : 0);

    for (int k0 = 0; k0 < F_IN; k0 += 4) {
        float4 xa = *(const float4*)(xr0 + k0);
        float4 xb = *(const float4*)(xr1 + k0);
        float ka[4] = {xa.x, xa.y, xa.z, xa.w};
        float kb[4] = {xb.x, xb.y, xb.z, xb.w};
        #pragma unroll
        for (int kk = 0; kk < 4; ++kk) {
            const float* wrow = &Ws[k0 + kk][j0];
            float4 w0 = *(const float4*)(wrow);
            float4 w1 = *(const float4*)(wrow + 4);
            float4 w2 = *(const float4*)(wrow + 8);
            float4 w3 = *(const float4*)(wrow + 12);
            float fa = ka[kk], fb = kb[kk];
            acc0[0]  += fa * w0.x; acc0[1]  += fa * w0.y;
            acc0[2]  += fa * w0.z; acc0[3]  += fa * w0.w;
            acc0[4]  += fa * w1.x; acc0[5]  += fa * w1.y;
            acc0[6]  += fa * w1.z; acc0[7]  += fa * w1.w;
            acc0[8]  += fa * w2.x; acc0[9]  += fa * w2.y;
            acc0[10] += fa * w2.z; acc0[11] += fa * w2.w;
            acc0[12] += fa * w3.x; acc0[13] += fa * w3.y;
            acc0[14] += fa * w3.z; acc0[15] += fa * w3.w;
            acc1[0]  += fb * w0.x; acc1[1]  += fb * w0.y;
            acc1[2]  += fb * w0.z; acc1[3]  += fb * w0.w;
            acc1[4]  += fb * w1.x; acc1[5]  += fb * w1.y;
            acc1[6]  += fb * w1.z; acc1[7]  += fb * w1.w;
            acc1[8]  += fb * w2.x; acc1[9]  += fb * w2.y;
            acc1[10] += fb * w2.z; acc1[11] += fb * w2.w;
            acc1[12] += fb * w3.x; acc1[13] += fb * w3.y;
            acc1[14] += fb * w3.z; acc1[15] += fb * w3.w;
        }
    }

    #pragma unroll
    for (int rr = 0; rr < 2; ++rr) {
        long gr = r0 + rr;
        if (rr == 1 && !v1) break;
        float* acc = (rr == 0) ? acc0 : acc1;
        float m = 0.0f;
        #pragma unroll
        for (int u = 0; u < 16; ++u)
            if (j0 + u < H) m = fmaxf(m, fabsf(acc[u]));
        m = fmaxf(m, __shfl_xor(m, 1));
        m = fmaxf(m, __shfl_xor(m, 2));
        m = fmaxf(m, 1e-12f);
        const float qmul  = 127.0f / m;
        const float scale = dinv[gr] * m * (1.0f / 127.0f);

        unsigned out[4] = {0u, 0u, 0u, 0u};
        #pragma unroll
        for (int u = 0; u < 16; ++u) {
            int q = 128;                   // bias: pad bytes decode to 0
            if (j0 + u < H) {
                int qi = (int)rintf(acc[u] * qmul);
                qi = max(-127, min(127, qi));
                q = qi + 128;
            }
            ((unsigned char*)out)[u] = (unsigned char)q;
        }
        if (jg == 3) out[1] = __float_as_uint(scale);   // byte 52 of row
        *(uint4v*)(h1q + gr * RB + jg * 16) = *(uint4v*)out;
    }
}

// CSR gather, 4 neighbors per wave step (R15-proven): lane = 16n+d loads
// dword d of neighbor n's 64 B row. Biased-ubyte decode + correction term.
__global__ __launch_bounds__(256) void k_agg1_fused(const int* __restrict__ rowptr,
                                                    const int* __restrict__ degn,
                                                    const int* __restrict__ colidx,
                                                    const unsigned char* __restrict__ h1q,
                                                    const float* __restrict__ dinv,
                                                    const float* __restrict__ b1,
                                                    const float* __restrict__ W2,
                                                    float* __restrict__ h2) {
    const int lane = threadIdx.x & 63;
    const int d = lane & 15;        // dword index in row
    const int n = lane >> 4;        // neighbor slot 0..3
    const int scLane = (lane & 48) | 13;

    float b1v[4], w20[4], w21[4];
    #pragma unroll
    for (int j = 0; j < 4; ++j) {
        int f = 4 * d + j;
        bool vld = f < H;
        b1v[j] = vld ? b1[f] : 0.0f;
        w20[j] = vld ? W2[f * 2 + 0] : 0.0f;
        w21[j] = vld ? W2[f * 2 + 1] : 0.0f;
    }

    long gw = ((long)blockIdx.x * blockDim.x + threadIdx.x) >> 6;
    long nwav = ((long)gridDim.x * blockDim.x) >> 6;
    for (long i = gw; i < N; i += nwav) {
        const int start = rowptr[i];
        const int deg   = degn[i];
        float a0 = 0.f, a1 = 0.f, a2 = 0.f, a3 = 0.f, corr = 0.f;

        {   // self row: only group n==0 contributes
            unsigned w = *(const unsigned*)(h1q + i * (long)RB + 4 * d);
            float sc = __uint_as_float(__shfl((int)w, scLane));
            if (n != 0) sc = 0.0f;
            a0 += (float)(w & 0xFFu) * sc;
            a1 += (float)((w >> 8) & 0xFFu) * sc;
            a2 += (float)((w >> 16) & 0xFFu) * sc;
            a3 += (float)(w >> 24) * sc;
            corr += sc;
        }
        int k = 0;
        for (; k + 8 <= deg; k += 8) {              // 2 independent 4-row loads
            int ia = colidx[start + k + n];
            int ib = colidx[start + k + 4 + n];
            unsigned wa = *(const unsigned*)(h1q + (long)ia * RB + 4 * d);
            unsigned wb = *(const unsigned*)(h1q + (long)ib * RB + 4 * d);
            float sa = __uint_as_float(__shfl((int)wa, scLane));
            float sb = __uint_as_float(__shfl((int)wb, scLane));
            a0 += (float)(wa & 0xFFu) * sa;
            a1 += (float)((wa >> 8) & 0xFFu) * sa;
            a2 += (float)((wa >> 16) & 0xFFu) * sa;
            a3 += (float)(wa >> 24) * sa;
            corr += sa;
            a0 += (float)(wb & 0xFFu) * sb;
            a1 += (float)((wb >> 8) & 0xFFu) * sb;
            a2 += (float)((wb >> 16) & 0xFFu) * sb;
            a3 += (float)(wb >> 24) * sb;
            corr += sb;
        }
        for (; k < deg; k += 4) {
            int kk = k + n;
            int idx = colidx[start + min(kk, deg - 1)];
            unsigned w = *(const unsigned*)(h1q + (long)idx * RB + 4 * d);
            float sc = __uint_as_float(__shfl((int)w, scLane));
            if (kk >= deg) sc = 0.0f;
            a0 += (float)(w & 0xFFu) * sc;
            a1 += (float)((w >> 8) & 0xFFu) * sc;
            a2 += (float)((w >> 16) & 0xFFu) * sc;
            a3 += (float)(w >> 24) * sc;
            corr += sc;
        }
        a0 -= 128.0f * corr;
        a1 -= 128.0f * corr;
        a2 -= 128.0f * corr;
        a3 -= 128.0f * corr;
        #pragma unroll
        for (int o = 16; o <= 32; o <<= 1) {
            a0 += __shfl_xor(a0, o);
            a1 += __shfl_xor(a1, o);
            a2 += __shfl_xor(a2, o);
            a3 += __shfl_xor(a3, o);
        }
        float di = dinv[i];
        float z0 = fmaxf(di * a0 + b1v[0], 0.0f);
        float z1 = fmaxf(di * a1 + b1v[1], 0.0f);
        float z2 = fmaxf(di * a2 + b1v[2], 0.0f);
        float z3 = fmaxf(di * a3 + b1v[3], 0.0f);
        float p0 = z0 * w20[0] + z1 * w20[1] + z2 * w20[2] + z3 * w20[3];
        float p1 = z0 * w21[0] + z1 * w21[1] + z2 * w21[2] + z3 * w21[3];
        #pragma unroll
        for (int o = 1; o <= 8; o <<= 1) {
            p0 += __shfl_xor(p0, o);
            p1 += __shfl_xor(p1, o);
        }
        if (lane == 0) {
            h2[i * 2 + 0] = di * p0;
            h2[i * 2 + 1] = di * p1;
        }
    }
}

// CSR wave-per-node, lanes over edges: out = log_softmax(di*(sum+self)+b2)
__global__ __launch_bounds__(256) void k_agg2_final(const int* __restrict__ rowptr,
                                                    const int* __restrict__ degn,
                                                    const int* __restrict__ colidx,
                                                    const float* __restrict__ h2,
                                                    const float* __restrict__ dinv,
                                                    const float* __restrict__ b2,
                                                    float* __restrict__ out) {
    const int lane = threadIdx.x & 63;
    long gw = ((long)blockIdx.x * blockDim.x + threadIdx.x) >> 6;
    long nwav = ((long)gridDim.x * blockDim.x) >> 6;
    for (long i = gw; i < N; i += nwav) {
        const int start = rowptr[i];
        const int deg   = degn[i];
        float s0 = 0.0f, s1 = 0.0f;
        for (int k = lane; k < deg; k += 64) {
            int s = colidx[start + k];
            s0 += h2[(long)s * 2 + 0];
            s1 += h2[(long)s * 2 + 1];
        }
        #pragma unroll
        for (int o = 32; o > 0; o >>= 1) {
            s0 += __shfl_xor(s0, o);
            s1 += __shfl_xor(s1, o);
        }
        if (lane == 0) {
            float di = dinv[i];
            float a0 = di * (s0 + h2[i * 2 + 0]) + b2[0];
            float a1 = di * (s1 + h2[i * 2 + 1]) + b2[1];
            float m = fmaxf(a0, a1);
            float lse = m + logf(expf(a0 - m) + expf(a1 - m));
            out[i * 2 + 0] = a0 - lse;
            out[i * 2 + 1] = a1 - lse;
        }
    }
}

extern "C" void kernel_launch(void* const* d_in, const int* in_sizes, int n_in,
                              void* d_out, int out_size, void* d_ws, size_t ws_size,
                              hipStream_t stream) {
    const float* x  = (const float*)d_in[0];
    const int*   ei = (const int*)d_in[1];   // [2][E]: row0 src, row1 dst
    const float* W1 = (const float*)d_in[2];
    const float* b1 = (const float*)d_in[3];
    const float* W2 = (const float*)d_in[4];
    const float* b2 = (const float*)d_in[5];
    float* out = (float*)d_out;

    const int* src = ei;
    const int* dst = ei + E;

    // ws layout
    int*    gcur   = (int*)d_ws;                       // 400
    int*    rowptr = gcur + 400;                       // N
    int*    degn   = rowptr + N;                       // N
    float*  dinv   = (float*)(degn + N);               // N
    int*    pairs  = (int*)(dinv + N);                 // NW*CAPW (14.4 MB)
    int*    colidx = pairs + (long)NW * CAPW;          // NW*CAPW (14.4 MB)
    unsigned char* h1q = (unsigned char*)(colidx + (long)NW * CAPW);  // 6.4 MB
    float*  h2     = (float*)(h1q + (long)N * RB);     // N*2  (~37 MB total)

    k_init<<<1, 512, 0, stream>>>(gcur);
    k_part<<<PART_BLK, 256, 0, stream>>>(src, dst, gcur, pairs);
    k_csrfill<<<NW, 512, 0, stream>>>(pairs, gcur, colidx, rowptr, degn, dinv);
    k_gemm1<<<(N + 127) / 128, 256, 0, stream>>>(x, W1, dinv, h1q);
    k_agg1_fused<<<4096, 256, 0, stream>>>(rowptr, degn, colidx, h1q, dinv, b1, W2, h2);
    k_agg2_final<<<2048, 256, 0, stream>>>(rowptr, degn, colidx, h2, dinv, b2, out);
}